// Round 9
// baseline (663.302 us; speedup 1.0000x reference)
//
#include <hip/hip_runtime.h>

// Bahdanau additive attention, f32 — DIAGNOSTIC ROUND: each kernel repeats
// its work REP_* times (idempotent recompute) so per-kernel time/counters
// become visible above the harness's ~40us 268MB ws-poison fills.
// B=8, TQ=128, TK=512, NIN=512, H=128, NV=512.

#define B_    8
#define TQ_   128
#define TK_   512
#define NIN_  512
#define H_    128
#define NV_   512
#define NQR   (B_*TQ_)           // 1024 query rows
#define NROWS (NQR + B_*TK_)     // 5120 projected rows

#define C2_   2.8853900817779268f   // 2*log2(e)
#define L2E_  1.4426950408889634f

#define REP_PROJ 12
#define REP_RED  32
#define REP_SC   10
#define REP_CTX  16

__device__ __forceinline__ float fexp2(float x){ return __builtin_amdgcn_exp2f(x); }
__device__ __forceinline__ float frcp (float x){ return __builtin_amdgcn_rcpf(x); }
__device__ __forceinline__ int opaque_zero() {
    int z; asm volatile("v_mov_b32 %0, 0" : "=v"(z)); return z;
}

// ---------------------------------------------------------------- proj ----
// psum[s][row][h] = A[row, ks:ke) . W[h, ks:ke)   (r4 form: best measured)
// 128 thr, tile 16 rows x 128 h, 4x4 microtile, kper=128, grid (320,4).
__global__ __launch_bounds__(128, 4) void proj_kernel(
        const float* __restrict__ query, const float* __restrict__ keys,
        const float* __restrict__ Wq, const float* __restrict__ Wk,
        float* __restrict__ psum, int kper) {
    __shared__ float at[32][20];
    __shared__ float wt[32][132];
    const int tid = threadIdx.x;
    const int r0  = blockIdx.x * 16;
    const float* in; const float* W;
    if (r0 < NQR) { in = query + (size_t)r0 * NIN_;         W = Wq; }
    else          { in = keys  + (size_t)(r0 - NQR) * NIN_; W = Wk; }

    const int r4 = (tid >> 5) * 4;       // 4 rows
    const int h4 = (tid & 31) * 4;       // 4 h
    const int sr  = tid >> 3;            // stage row 0..15
    const int skq = (tid & 7) * 4;       // stage k quad
    const int kb0 = blockIdx.y * kper;
    const int nc  = kper >> 5;

    for (int rep = 0; rep < REP_PROJ; ++rep) {
        const float* pA  = in + (size_t)sr * NIN_ + kb0 + skq;
        const float* pW0 = W + (size_t)(sr      ) * NIN_ + kb0 + skq;
        const float* pW1 = W + (size_t)(sr + 16 ) * NIN_ + kb0 + skq;
        const float* pW2 = W + (size_t)(sr + 32 ) * NIN_ + kb0 + skq;
        const float* pW3 = W + (size_t)(sr + 48 ) * NIN_ + kb0 + skq;
        const float* pW4 = W + (size_t)(sr + 64 ) * NIN_ + kb0 + skq;
        const float* pW5 = W + (size_t)(sr + 80 ) * NIN_ + kb0 + skq;
        const float* pW6 = W + (size_t)(sr + 96 ) * NIN_ + kb0 + skq;
        const float* pW7 = W + (size_t)(sr + 112) * NIN_ + kb0 + skq;

        float4 af = *(const float4*)pA;
        float4 w0 = *(const float4*)pW0, w1 = *(const float4*)pW1;
        float4 w2 = *(const float4*)pW2, w3 = *(const float4*)pW3;
        float4 w4 = *(const float4*)pW4, w5 = *(const float4*)pW5;
        float4 w6 = *(const float4*)pW6, w7 = *(const float4*)pW7;

        float acc[4][4];
#pragma unroll
        for (int i = 0; i < 4; ++i)
#pragma unroll
            for (int j = 0; j < 4; ++j) acc[i][j] = 0.0f;

        for (int c = 0; c < nc; ++c) {
            __syncthreads();
            at[skq+0][sr] = af.x; at[skq+1][sr] = af.y;
            at[skq+2][sr] = af.z; at[skq+3][sr] = af.w;
            wt[skq+0][sr    ] = w0.x; wt[skq+1][sr    ] = w0.y;
            wt[skq+2][sr    ] = w0.z; wt[skq+3][sr    ] = w0.w;
            wt[skq+0][sr+ 16] = w1.x; wt[skq+1][sr+ 16] = w1.y;
            wt[skq+2][sr+ 16] = w1.z; wt[skq+3][sr+ 16] = w1.w;
            wt[skq+0][sr+ 32] = w2.x; wt[skq+1][sr+ 32] = w2.y;
            wt[skq+2][sr+ 32] = w2.z; wt[skq+3][sr+ 32] = w2.w;
            wt[skq+0][sr+ 48] = w3.x; wt[skq+1][sr+ 48] = w3.y;
            wt[skq+2][sr+ 48] = w3.z; wt[skq+3][sr+ 48] = w3.w;
            wt[skq+0][sr+ 64] = w4.x; wt[skq+1][sr+ 64] = w4.y;
            wt[skq+2][sr+ 64] = w4.z; wt[skq+3][sr+ 64] = w4.w;
            wt[skq+0][sr+ 80] = w5.x; wt[skq+1][sr+ 80] = w5.y;
            wt[skq+2][sr+ 80] = w5.z; wt[skq+3][sr+ 80] = w5.w;
            wt[skq+0][sr+ 96] = w6.x; wt[skq+1][sr+ 96] = w6.y;
            wt[skq+2][sr+ 96] = w6.z; wt[skq+3][sr+ 96] = w6.w;
            wt[skq+0][sr+112] = w7.x; wt[skq+1][sr+112] = w7.y;
            wt[skq+2][sr+112] = w7.z; wt[skq+3][sr+112] = w7.w;
            __syncthreads();
            if (c + 1 < nc) {
                pA += 32; pW0 += 32; pW1 += 32; pW2 += 32; pW3 += 32;
                pW4 += 32; pW5 += 32; pW6 += 32; pW7 += 32;
                af = *(const float4*)pA;
                w0 = *(const float4*)pW0; w1 = *(const float4*)pW1;
                w2 = *(const float4*)pW2; w3 = *(const float4*)pW3;
                w4 = *(const float4*)pW4; w5 = *(const float4*)pW5;
                w6 = *(const float4*)pW6; w7 = *(const float4*)pW7;
            }
#pragma unroll 8
            for (int kk = 0; kk < 32; ++kk) {
                float4 a = *(const float4*)&at[kk][r4];
                float4 w = *(const float4*)&wt[kk][h4];
                float av[4] = {a.x, a.y, a.z, a.w};
                float wv[4] = {w.x, w.y, w.z, w.w};
#pragma unroll
                for (int i = 0; i < 4; ++i)
#pragma unroll
                    for (int j = 0; j < 4; ++j)
                        acc[i][j] = fmaf(av[i], wv[j], acc[i][j]);
            }
        }

        float* op = psum + ((size_t)blockIdx.y * NROWS + r0) * H_;
#pragma unroll
        for (int i = 0; i < 4; ++i) {
            float4 o = {acc[i][0], acc[i][1], acc[i][2], acc[i][3]};
            *(float4*)&op[(size_t)(r4 + i) * H_ + h4] = o;
        }
    }
}

// -------------------------------------------------------------- reduce ----
// pout[row][h] = (sum_s psum[s][row][h] + bias[h]) * C2  (pre-scale folded)
// 8 rows/block, 640 blocks.
__global__ __launch_bounds__(256, 4) void reduce_kernel(
        const float* __restrict__ psum, const float* __restrict__ bq,
        const float* __restrict__ bk, float* __restrict__ pout) {
    const int tid = threadIdx.x;
    const int r0  = blockIdx.x * 8;
    const float* bias = (r0 < NQR) ? bq : bk;
    const int row = tid >> 5, hq = (tid & 31) * 4;

    for (int rep = 0; rep < REP_RED; ++rep) {
        const int z = opaque_zero();          // defeat load hoisting across reps
        const float* ps = psum + z;
        float4 s = *(const float4*)&bias[hq];
#pragma unroll
        for (int sp = 0; sp < 4; ++sp) {
            float4 v = *(const float4*)&ps[((size_t)sp * NROWS + r0 + row) * H_ + hq];
            s.x += v.x; s.y += v.y; s.z += v.z; s.w += v.w;
        }
        float4 o = {s.x * C2_, s.y * C2_, s.z * C2_, s.w * C2_};
        *(float4*)&pout[(size_t)(r0 + row) * H_ + hq] = o;
        __syncthreads();
    }
}

// -------------------------------------------------------------- scores ----
// Per block: batch b, 2 q rows. Inputs pre-scaled by C2 (bias folded).
__global__ __launch_bounds__(256, 4) void scores_kernel(
        const float* __restrict__ qp, const float* __restrict__ kp,
        const float* __restrict__ Wo, const float* __restrict__ bo,
        float* __restrict__ out_attn) {
    __shared__ float qs2[2][H_];
    __shared__ float w2[H_];
    __shared__ float sc[2][TK_];

    const int tid = threadIdx.x;
    const int b   = blockIdx.y;
    const int q0  = blockIdx.x * 2;
    const int lane = tid & 63;

    for (int rep = 0; rep < REP_SC; ++rep) {
        qs2[tid >> 7][tid & 127] =
            qp[(size_t)(b * TQ_ + q0 + (tid >> 7)) * H_ + (tid & 127)];
        if (tid < H_) w2[tid] = Wo[tid] * -2.0f;
        __syncthreads();

        float sw = w2[lane] + w2[lane + 64];
#pragma unroll
        for (int m = 1; m < 64; m <<= 1) sw += __shfl_xor(sw, m);
        const float sbase = bo[0] - 0.5f * sw;

#pragma unroll
        for (int half = 0; half < 2; ++half) {
            const int k = tid + half * 256;
            const float4* kp4 = (const float4*)&kp[(size_t)(b * TK_ + k) * H_];
            float s0 = 0.f, s1 = 0.f;
#pragma unroll 4
            for (int hb = 0; hb < 32; ++hb) {
                const float4 kv  = kp4[hb];
                const float4 wv  = *(const float4*)&w2[hb * 4];
                const float4 q0v = *(const float4*)&qs2[0][hb * 4];
                const float4 q1v = *(const float4*)&qs2[1][hb * 4];
                s0 = fmaf(wv.x, frcp(fexp2(q0v.x + kv.x) + 1.f), s0);
                s0 = fmaf(wv.y, frcp(fexp2(q0v.y + kv.y) + 1.f), s0);
                s0 = fmaf(wv.z, frcp(fexp2(q0v.z + kv.z) + 1.f), s0);
                s0 = fmaf(wv.w, frcp(fexp2(q0v.w + kv.w) + 1.f), s0);
                s1 = fmaf(wv.x, frcp(fexp2(q1v.x + kv.x) + 1.f), s1);
                s1 = fmaf(wv.y, frcp(fexp2(q1v.y + kv.y) + 1.f), s1);
                s1 = fmaf(wv.z, frcp(fexp2(q1v.z + kv.z) + 1.f), s1);
                s1 = fmaf(wv.w, frcp(fexp2(q1v.w + kv.w) + 1.f), s1);
            }
            sc[0][k] = s0 + sbase;
            sc[1][k] = s1 + sbase;
        }
        __syncthreads();

        const int w = tid >> 6;
        if (w < 2) {
            float4 sA = *(const float4*)&sc[w][lane * 8];
            float4 sB = *(const float4*)&sc[w][lane * 8 + 4];
            float m = fmaxf(fmaxf(fmaxf(sA.x, sA.y), fmaxf(sA.z, sA.w)),
                            fmaxf(fmaxf(sB.x, sB.y), fmaxf(sB.z, sB.w)));
#pragma unroll
            for (int mk = 1; mk < 64; mk <<= 1) m = fmaxf(m, __shfl_xor(m, mk));
            float4 eA, eB;
            eA.x = fexp2((sA.x - m) * L2E_); eA.y = fexp2((sA.y - m) * L2E_);
            eA.z = fexp2((sA.z - m) * L2E_); eA.w = fexp2((sA.w - m) * L2E_);
            eB.x = fexp2((sB.x - m) * L2E_); eB.y = fexp2((sB.y - m) * L2E_);
            eB.z = fexp2((sB.z - m) * L2E_); eB.w = fexp2((sB.w - m) * L2E_);
            float s = eA.x + eA.y + eA.z + eA.w + eB.x + eB.y + eB.z + eB.w;
#pragma unroll
            for (int mk = 1; mk < 64; mk <<= 1) s += __shfl_xor(s, mk);
            const float inv = frcp(s);
            eA.x *= inv; eA.y *= inv; eA.z *= inv; eA.w *= inv;
            eB.x *= inv; eB.y *= inv; eB.z *= inv; eB.w *= inv;
            float4* op = (float4*)&out_attn[(size_t)(b * TQ_ + q0 + w) * TK_ + lane * 8];
            op[0] = eA; op[1] = eB;
        }
        __syncthreads();
    }
}

// ------------------------------------------------------------- context ----
// 128 thr, 8 q x 64 v, full K=512, 2x2 microtile, reg prefetch. 1024 blocks.
__global__ __launch_bounds__(128, 4) void context_kernel(
        const float* __restrict__ attn, const float* __restrict__ values,
        float* __restrict__ outc) {
    __shared__ float at[32][12];
    __shared__ float vt[32][68];

    const int tid = threadIdx.x;
    const int b   = blockIdx.y;
    const int q0  = (blockIdx.x >> 3) * 8;
    const int v0  = (blockIdx.x & 7) * 64;

    const int v2 = (tid & 31) * 2;
    const int q2 = (tid >> 5) * 2;
    const int ar  = tid >> 3;
    const int akq = (tid & 7) * 4;
    const int vr  = tid >> 4;
    const int vq  = (tid & 15) * 4;

    for (int rep = 0; rep < REP_CTX; ++rep) {
        const float* pAt = attn + (size_t)(b * TQ_ + q0 + ar) * TK_ + akq;
        const float* pV0 = values + (size_t)(b * TK_ + vr     ) * NV_ + v0 + vq;
        const float* pV1 = values + (size_t)(b * TK_ + vr +  8) * NV_ + v0 + vq;
        const float* pV2 = values + (size_t)(b * TK_ + vr + 16) * NV_ + v0 + vq;
        const float* pV3 = values + (size_t)(b * TK_ + vr + 24) * NV_ + v0 + vq;

        float4 af = {0.f,0.f,0.f,0.f};
        if (tid < 64) af = *(const float4*)pAt;
        float4 vf0 = *(const float4*)pV0;
        float4 vf1 = *(const float4*)pV1;
        float4 vf2 = *(const float4*)pV2;
        float4 vf3 = *(const float4*)pV3;

        float acc[2][2] = {{0.f,0.f},{0.f,0.f}};

        for (int c = 0; c < 16; ++c) {
            __syncthreads();
            if (tid < 64) {
                at[akq+0][ar] = af.x; at[akq+1][ar] = af.y;
                at[akq+2][ar] = af.z; at[akq+3][ar] = af.w;
            }
            *(float4*)&vt[vr     ][vq] = vf0;
            *(float4*)&vt[vr +  8][vq] = vf1;
            *(float4*)&vt[vr + 16][vq] = vf2;
            *(float4*)&vt[vr + 24][vq] = vf3;
            __syncthreads();
            if (c + 1 < 16) {
                pAt += 32; pV0 += 32 * NV_; pV1 += 32 * NV_;
                pV2 += 32 * NV_; pV3 += 32 * NV_;
                if (tid < 64) af = *(const float4*)pAt;
                vf0 = *(const float4*)pV0; vf1 = *(const float4*)pV1;
                vf2 = *(const float4*)pV2; vf3 = *(const float4*)pV3;
            }
#pragma unroll 8
            for (int kk = 0; kk < 32; ++kk) {
                const float2 a = *(const float2*)&at[kk][q2];
                const float2 v = *(const float2*)&vt[kk][v2];
                acc[0][0] = fmaf(a.x, v.x, acc[0][0]);
                acc[0][1] = fmaf(a.x, v.y, acc[0][1]);
                acc[1][0] = fmaf(a.y, v.x, acc[1][0]);
                acc[1][1] = fmaf(a.y, v.y, acc[1][1]);
            }
        }
        float2 o0 = {acc[0][0], acc[0][1]};
        float2 o1 = {acc[1][0], acc[1][1]};
        *(float2*)&outc[(size_t)(b * TQ_ + q0 + q2 + 0) * NV_ + v0 + v2] = o0;
        *(float2*)&outc[(size_t)(b * TQ_ + q0 + q2 + 1) * NV_ + v0 + v2] = o1;
        __syncthreads();
    }
}

// -------------------------------------------------------------- launch ----
extern "C" void kernel_launch(void* const* d_in, const int* in_sizes, int n_in,
                              void* d_out, int out_size, void* d_ws, size_t ws_size,
                              hipStream_t stream) {
    const float* query  = (const float*)d_in[0];
    const float* keys   = (const float*)d_in[1];
    const float* values = (const float*)d_in[2];
    const float* Wq     = (const float*)d_in[3];
    const float* bq     = (const float*)d_in[4];
    const float* Wk     = (const float*)d_in[5];
    const float* bk     = (const float*)d_in[6];
    const float* Wo     = (const float*)d_in[7];
    const float* bo     = (const float*)d_in[8];

    float* out_ctx  = (float*)d_out;                 // B*TQ*NV
    float* out_attn = out_ctx + B_ * TQ_ * NV_;      // B*TQ*TK
    float* pout = (float*)d_ws;                      // NROWS*H (qp then kp, *C2)
    float* qp = pout;
    float* kp = pout + (size_t)NQR * H_;
    float* psum = pout + (size_t)NROWS * H_;         // 4*NROWS*H

    proj_kernel<<<dim3(NROWS / 16, 4), 128, 0, stream>>>(
        query, keys, Wq, Wk, psum, NIN_ / 4);
    reduce_kernel<<<NROWS / 8, 256, 0, stream>>>(psum, bq, bk, pout);
    scores_kernel<<<dim3(TQ_ / 2, B_), 256, 0, stream>>>(qp, kp, Wo, bo, out_attn);
    context_kernel<<<dim3(128, B_), 128, 0, stream>>>(out_attn, values, out_ctx);
}

// Round 10
// 66.101 us; speedup vs baseline: 10.0347x; 10.0347x over previous
//
#include <hip/hip_runtime.h>

// Bahdanau additive attention, f32, 5 kernels, split-K on both GEMMs.
// B=8, TQ=128, TK=512, NIN=512, H=128, NV=512.
// out = [context (B*TQ*NV), attn (B*TQ*TK)] f32.

#define B_    8
#define TQ_   128
#define TK_   512
#define NIN_  512
#define H_    128
#define NV_   512
#define NQR   (B_*TQ_)           // 1024 query rows
#define NROWS (NQR + B_*TK_)     // 5120 projected rows
#define CTXN  (B_*TQ_*NV_)       // 524288 context elems

#define C2_   2.8853900817779268f   // 2*log2(e)
#define L2E_  1.4426950408889634f

__device__ __forceinline__ float fexp2(float x){ return __builtin_amdgcn_exp2f(x); }
__device__ __forceinline__ float frcp (float x){ return __builtin_amdgcn_rcpf(x); }

// ---------------------------------------------------------------- proj ----
// psum[s][row][h] = A[row, ks:ke) . W[h, ks:ke)
// 256 thr, tile 16 rows x 128 h, 2x4 microtile, kper=128 (4 chunks of 32).
// grid (320, 4) = 1280 blocks x 4 waves = 5 waves/SIMD.
__global__ __launch_bounds__(256, 5) void proj_kernel(
        const float* __restrict__ query, const float* __restrict__ keys,
        const float* __restrict__ Wq, const float* __restrict__ Wk,
        float* __restrict__ psum, int kper) {
    __shared__ float at[32][18];     // [kk][row], 16 rows
    __shared__ float wt[32][132];    // [kk][h], 128 h
    const int tid = threadIdx.x;
    const int r0  = blockIdx.x * 16;
    const float* in; const float* W;
    if (r0 < NQR) { in = query + (size_t)r0 * NIN_;         W = Wq; }
    else          { in = keys  + (size_t)(r0 - NQR) * NIN_; W = Wk; }

    const int r2 = (tid >> 5) * 2;       // 2 rows
    const int h4 = (tid & 31) * 4;       // 4 h
    const int ar  = tid >> 4;            // A-stage row 0..15
    const int ak2 = (tid & 15) * 2;      // A-stage k pair
    const int wr  = tid >> 3;            // W-stage h 0..31 (+32p)
    const int wkq = (tid & 7) * 4;       // W-stage k quad
    const int kb0 = blockIdx.y * kper;
    const int nc  = kper >> 5;

    const float* pA  = in + (size_t)ar * NIN_ + kb0 + ak2;
    const float* pW0 = W + (size_t)(wr     ) * NIN_ + kb0 + wkq;
    const float* pW1 = W + (size_t)(wr + 32) * NIN_ + kb0 + wkq;
    const float* pW2 = W + (size_t)(wr + 64) * NIN_ + kb0 + wkq;
    const float* pW3 = W + (size_t)(wr + 96) * NIN_ + kb0 + wkq;

    float2 af = *(const float2*)pA;
    float4 w0 = *(const float4*)pW0, w1 = *(const float4*)pW1;
    float4 w2 = *(const float4*)pW2, w3 = *(const float4*)pW3;

    float acc[2][4] = {{0.f,0.f,0.f,0.f},{0.f,0.f,0.f,0.f}};

    for (int c = 0; c < nc; ++c) {
        __syncthreads();
        at[ak2+0][ar] = af.x; at[ak2+1][ar] = af.y;
        wt[wkq+0][wr   ] = w0.x; wt[wkq+1][wr   ] = w0.y;
        wt[wkq+2][wr   ] = w0.z; wt[wkq+3][wr   ] = w0.w;
        wt[wkq+0][wr+32] = w1.x; wt[wkq+1][wr+32] = w1.y;
        wt[wkq+2][wr+32] = w1.z; wt[wkq+3][wr+32] = w1.w;
        wt[wkq+0][wr+64] = w2.x; wt[wkq+1][wr+64] = w2.y;
        wt[wkq+2][wr+64] = w2.z; wt[wkq+3][wr+64] = w2.w;
        wt[wkq+0][wr+96] = w3.x; wt[wkq+1][wr+96] = w3.y;
        wt[wkq+2][wr+96] = w3.z; wt[wkq+3][wr+96] = w3.w;
        __syncthreads();
        if (c + 1 < nc) {
            pA += 32; pW0 += 32; pW1 += 32; pW2 += 32; pW3 += 32;
            af = *(const float2*)pA;
            w0 = *(const float4*)pW0; w1 = *(const float4*)pW1;
            w2 = *(const float4*)pW2; w3 = *(const float4*)pW3;
        }
#pragma unroll 8
        for (int kk = 0; kk < 32; ++kk) {
            const float2 a = *(const float2*)&at[kk][r2];
            const float4 w = *(const float4*)&wt[kk][h4];
            acc[0][0] = fmaf(a.x, w.x, acc[0][0]);
            acc[0][1] = fmaf(a.x, w.y, acc[0][1]);
            acc[0][2] = fmaf(a.x, w.z, acc[0][2]);
            acc[0][3] = fmaf(a.x, w.w, acc[0][3]);
            acc[1][0] = fmaf(a.y, w.x, acc[1][0]);
            acc[1][1] = fmaf(a.y, w.y, acc[1][1]);
            acc[1][2] = fmaf(a.y, w.z, acc[1][2]);
            acc[1][3] = fmaf(a.y, w.w, acc[1][3]);
        }
    }

    float* op = psum + ((size_t)blockIdx.y * NROWS + r0) * H_;
#pragma unroll
    for (int i = 0; i < 2; ++i) {
        float4 o = {acc[i][0], acc[i][1], acc[i][2], acc[i][3]};
        *(float4*)&op[(size_t)(r2 + i) * H_ + h4] = o;
    }
}

// ------------------------------------------------------------- reduceP ----
// pout[row][h] = (sum_s psum[s][row][h] + bias[h]) * C2
__global__ __launch_bounds__(256, 4) void reduceP_kernel(
        const float* __restrict__ psum, const float* __restrict__ bq,
        const float* __restrict__ bk, float* __restrict__ pout) {
    const int tid = threadIdx.x;
    const int r0  = blockIdx.x * 8;
    const float* bias = (r0 < NQR) ? bq : bk;
    const int row = tid >> 5, hq = (tid & 31) * 4;
    float4 s = *(const float4*)&bias[hq];
#pragma unroll
    for (int sp = 0; sp < 4; ++sp) {
        float4 v = *(const float4*)&psum[((size_t)sp * NROWS + r0 + row) * H_ + hq];
        s.x += v.x; s.y += v.y; s.z += v.z; s.w += v.w;
    }
    float4 o = {s.x * C2_, s.y * C2_, s.z * C2_, s.w * C2_};
    *(float4*)&pout[(size_t)(r0 + row) * H_ + hq] = o;
}

// -------------------------------------------------------------- scores ----
// Per block: batch b, 2 q rows. Inputs pre-scaled by C2 (bias folded).
// score = bo + sumWo - 2*sum_h Wo_h/(e^(2x_h)+1); softmax over k.
__global__ __launch_bounds__(256, 4) void scores_kernel(
        const float* __restrict__ qp, const float* __restrict__ kp,
        const float* __restrict__ Wo, const float* __restrict__ bo,
        float* __restrict__ out_attn) {
    __shared__ float qs2[2][H_];
    __shared__ float w2[H_];
    __shared__ float sc[2][TK_];

    const int tid = threadIdx.x;
    const int b   = blockIdx.y;
    const int q0  = blockIdx.x * 2;
    const int lane = tid & 63;

    qs2[tid >> 7][tid & 127] =
        qp[(size_t)(b * TQ_ + q0 + (tid >> 7)) * H_ + (tid & 127)];
    if (tid < H_) w2[tid] = Wo[tid] * -2.0f;
    __syncthreads();

    float sw = w2[lane] + w2[lane + 64];
#pragma unroll
    for (int m = 1; m < 64; m <<= 1) sw += __shfl_xor(sw, m);
    const float sbase = bo[0] - 0.5f * sw;

#pragma unroll
    for (int half = 0; half < 2; ++half) {
        const int k = tid + half * 256;
        const float4* kp4 = (const float4*)&kp[(size_t)(b * TK_ + k) * H_];
        float s0 = 0.f, s1 = 0.f;
#pragma unroll 4
        for (int hb = 0; hb < 32; ++hb) {
            const float4 kv  = kp4[hb];
            const float4 wv  = *(const float4*)&w2[hb * 4];
            const float4 q0v = *(const float4*)&qs2[0][hb * 4];
            const float4 q1v = *(const float4*)&qs2[1][hb * 4];
            s0 = fmaf(wv.x, frcp(fexp2(q0v.x + kv.x) + 1.f), s0);
            s0 = fmaf(wv.y, frcp(fexp2(q0v.y + kv.y) + 1.f), s0);
            s0 = fmaf(wv.z, frcp(fexp2(q0v.z + kv.z) + 1.f), s0);
            s0 = fmaf(wv.w, frcp(fexp2(q0v.w + kv.w) + 1.f), s0);
            s1 = fmaf(wv.x, frcp(fexp2(q1v.x + kv.x) + 1.f), s1);
            s1 = fmaf(wv.y, frcp(fexp2(q1v.y + kv.y) + 1.f), s1);
            s1 = fmaf(wv.z, frcp(fexp2(q1v.z + kv.z) + 1.f), s1);
            s1 = fmaf(wv.w, frcp(fexp2(q1v.w + kv.w) + 1.f), s1);
        }
        sc[0][k] = s0 + sbase;
        sc[1][k] = s1 + sbase;
    }
    __syncthreads();

    const int w = tid >> 6;
    if (w < 2) {
        float4 sA = *(const float4*)&sc[w][lane * 8];
        float4 sB = *(const float4*)&sc[w][lane * 8 + 4];
        float m = fmaxf(fmaxf(fmaxf(sA.x, sA.y), fmaxf(sA.z, sA.w)),
                        fmaxf(fmaxf(sB.x, sB.y), fmaxf(sB.z, sB.w)));
#pragma unroll
        for (int mk = 1; mk < 64; mk <<= 1) m = fmaxf(m, __shfl_xor(m, mk));
        float4 eA, eB;
        eA.x = fexp2((sA.x - m) * L2E_); eA.y = fexp2((sA.y - m) * L2E_);
        eA.z = fexp2((sA.z - m) * L2E_); eA.w = fexp2((sA.w - m) * L2E_);
        eB.x = fexp2((sB.x - m) * L2E_); eB.y = fexp2((sB.y - m) * L2E_);
        eB.z = fexp2((sB.z - m) * L2E_); eB.w = fexp2((sB.w - m) * L2E_);
        float s = eA.x + eA.y + eA.z + eA.w + eB.x + eB.y + eB.z + eB.w;
#pragma unroll
        for (int mk = 1; mk < 64; mk <<= 1) s += __shfl_xor(s, mk);
        const float inv = frcp(s);
        eA.x *= inv; eA.y *= inv; eA.z *= inv; eA.w *= inv;
        eB.x *= inv; eB.y *= inv; eB.z *= inv; eB.w *= inv;
        float4* op = (float4*)&out_attn[(size_t)(b * TQ_ + q0 + w) * TK_ + lane * 8];
        op[0] = eA; op[1] = eB;
    }
}

// ------------------------------------------------------------- context ----
// psumC[z][b,q,v] = sum_{k in z-chunk} attn[b,q,k] * V[b,k,v]
// 128 thr, tile 16 q x 64 v, kper=128 (4 chunks of 32), 2q x 4v microtile.
// grid (64, 8, 4) = 2048 blocks x 2 waves = 4 waves/SIMD.
__global__ __launch_bounds__(128, 4) void context_kernel(
        const float* __restrict__ attn, const float* __restrict__ values,
        float* __restrict__ psumC) {
    __shared__ float at[32][18];    // [kk][q], 16 q
    __shared__ float vt[32][68];    // [kk][v], 64 v

    const int tid = threadIdx.x;
    const int r0  = blockIdx.x * 16;         // global q row (over B*TQ)
    const int b   = r0 >> 7;
    const int v0  = blockIdx.y * 64;
    const int kb0 = blockIdx.z * 128;

    const int q2 = (tid >> 4) * 2;           // 2 q
    const int v4 = (tid & 15) * 4;           // 4 v
    const int ar  = tid >> 3;                // attn stage row 0..15
    const int akq = (tid & 7) * 4;
    const int vr  = tid >> 4;                // values stage row 0..7 (+8p)
    const int vq  = (tid & 15) * 4;

    const float* pAt = attn + (size_t)(r0 + ar) * TK_ + kb0 + akq;
    const float* pV0 = values + (size_t)(b * TK_ + kb0 + vr     ) * NV_ + v0 + vq;
    const float* pV1 = values + (size_t)(b * TK_ + kb0 + vr +  8) * NV_ + v0 + vq;
    const float* pV2 = values + (size_t)(b * TK_ + kb0 + vr + 16) * NV_ + v0 + vq;
    const float* pV3 = values + (size_t)(b * TK_ + kb0 + vr + 24) * NV_ + v0 + vq;

    float4 af  = *(const float4*)pAt;
    float4 vf0 = *(const float4*)pV0;
    float4 vf1 = *(const float4*)pV1;
    float4 vf2 = *(const float4*)pV2;
    float4 vf3 = *(const float4*)pV3;

    float acc[2][4] = {{0.f,0.f,0.f,0.f},{0.f,0.f,0.f,0.f}};

    for (int c = 0; c < 4; ++c) {
        __syncthreads();
        at[akq+0][ar] = af.x; at[akq+1][ar] = af.y;
        at[akq+2][ar] = af.z; at[akq+3][ar] = af.w;
        *(float4*)&vt[vr     ][vq] = vf0;
        *(float4*)&vt[vr +  8][vq] = vf1;
        *(float4*)&vt[vr + 16][vq] = vf2;
        *(float4*)&vt[vr + 24][vq] = vf3;
        __syncthreads();
        if (c + 1 < 4) {
            pAt += 32; pV0 += 32 * NV_; pV1 += 32 * NV_;
            pV2 += 32 * NV_; pV3 += 32 * NV_;
            af  = *(const float4*)pAt;
            vf0 = *(const float4*)pV0; vf1 = *(const float4*)pV1;
            vf2 = *(const float4*)pV2; vf3 = *(const float4*)pV3;
        }
#pragma unroll 8
        for (int kk = 0; kk < 32; ++kk) {
            const float2 a = *(const float2*)&at[kk][q2];
            const float4 v = *(const float4*)&vt[kk][v4];
            acc[0][0] = fmaf(a.x, v.x, acc[0][0]);
            acc[0][1] = fmaf(a.x, v.y, acc[0][1]);
            acc[0][2] = fmaf(a.x, v.z, acc[0][2]);
            acc[0][3] = fmaf(a.x, v.w, acc[0][3]);
            acc[1][0] = fmaf(a.y, v.x, acc[1][0]);
            acc[1][1] = fmaf(a.y, v.y, acc[1][1]);
            acc[1][2] = fmaf(a.y, v.z, acc[1][2]);
            acc[1][3] = fmaf(a.y, v.w, acc[1][3]);
        }
    }

    float* op = psumC + (size_t)blockIdx.z * CTXN + (size_t)r0 * NV_ + v0;
#pragma unroll
    for (int i = 0; i < 2; ++i) {
        float4 o = {acc[i][0], acc[i][1], acc[i][2], acc[i][3]};
        *(float4*)&op[(size_t)(q2 + i) * NV_ + v4] = o;
    }
}

// ------------------------------------------------------------- reduceC ----
// out_ctx[i] = sum_z psumC[z][i]
__global__ __launch_bounds__(256, 4) void reduceC_kernel(
        const float* __restrict__ psumC, float* __restrict__ outc) {
    const size_t i = ((size_t)blockIdx.x * 256 + threadIdx.x) * 4;
    float4 s = *(const float4*)&psumC[i];
#pragma unroll
    for (int z = 1; z < 4; ++z) {
        float4 v = *(const float4*)&psumC[(size_t)z * CTXN + i];
        s.x += v.x; s.y += v.y; s.z += v.z; s.w += v.w;
    }
    *(float4*)&outc[i] = s;
}

// -------------------------------------------------------------- launch ----
extern "C" void kernel_launch(void* const* d_in, const int* in_sizes, int n_in,
                              void* d_out, int out_size, void* d_ws, size_t ws_size,
                              hipStream_t stream) {
    const float* query  = (const float*)d_in[0];
    const float* keys   = (const float*)d_in[1];
    const float* values = (const float*)d_in[2];
    const float* Wq     = (const float*)d_in[3];
    const float* bq     = (const float*)d_in[4];
    const float* Wk     = (const float*)d_in[5];
    const float* bk     = (const float*)d_in[6];
    const float* Wo     = (const float*)d_in[7];
    const float* bo     = (const float*)d_in[8];

    float* out_ctx  = (float*)d_out;                 // B*TQ*NV
    float* out_attn = out_ctx + B_ * TQ_ * NV_;      // B*TQ*TK
    float* pout  = (float*)d_ws;                     // NROWS*H (qp,kp; *C2)
    float* qp    = pout;
    float* kp    = pout + (size_t)NQR * H_;
    float* psumP = pout + (size_t)NROWS * H_;        // 4*NROWS*H
    float* psumC = psumP + (size_t)4 * NROWS * H_;   // 4*CTXN

    proj_kernel<<<dim3(NROWS / 16, 4), 256, 0, stream>>>(
        query, keys, Wq, Wk, psumP, NIN_ / 4);
    reduceP_kernel<<<NROWS / 8, 256, 0, stream>>>(psumP, bq, bk, pout);
    scores_kernel<<<dim3(TQ_ / 2, B_), 256, 0, stream>>>(qp, kp, Wo, bo, out_attn);
    context_kernel<<<dim3(NQR / 16, NV_ / 64, 4), 128, 0, stream>>>(
        out_attn, values, psumC);
    reduceC_kernel<<<CTXN / 1024, 256, 0, stream>>>(psumC, out_ctx);
}